// Round 8
// baseline (806.376 us; speedup 1.0000x reference)
//
#include <hip/hip_runtime.h>
#include <hip/hip_bf16.h>

#define TPB 256
#define BSHIFT 7                 // 128 nodes per bucket
#define BNODES (1 << BSHIFT)
#define NWRITERS 256             // edge-chunk writer blocks

typedef int vint4 __attribute__((ext_vector_type(4)));

// f32 -> bf16 bits, RNE
__device__ __forceinline__ unsigned short f2bf(float f) {
    unsigned int u = __float_as_uint(f);
    u += 0x7fffu + ((u >> 16) & 1u);
    return (unsigned short)(u >> 16);
}
__device__ __forceinline__ float bflo(unsigned int u) { return __uint_as_float(u << 16); }
__device__ __forceinline__ float bfhi(unsigned int u) { return __uint_as_float(u & 0xffff0000u); }

// ---------------- K1: fused  [gemm1: xl = x@W1+b1 -> bf16]  +  [hist: per-chunk bucket counts] ----
__global__ __launch_bounds__(TPB) void k_gemm1_hist(
    const float* __restrict__ x, const float* __restrict__ W1, const float* __restrict__ b1,
    unsigned int* __restrict__ xlb,
    const int* __restrict__ ei, int* __restrict__ cnt,   // cnt[writer*NB + bucket]
    int N, int E, int NB, int CH, int nbG)
{
    __shared__ float w1s[128 * 64];
    __shared__ float xs[64 * 132];
    __shared__ float b1s[64];
    __shared__ int   lcnt[1024];

    const int t = threadIdx.x;

    if ((int)blockIdx.x >= nbG) {
        // ---- histogram part: writer block hb counts its private chunk ----
        const int hb = blockIdx.x - nbG;
        const int start = hb * CH;
        const int lim = min(E, start + CH);
        for (int j = t; j < NB; j += TPB) lcnt[j] = 0;
        __syncthreads();
        const int* dst = ei + E;
        int i = start + t * 4;
        for (; i + 3 < lim; i += TPB * 4) {
            vint4 d = __builtin_nontemporal_load(reinterpret_cast<const vint4*>(dst + i));
            atomicAdd(&lcnt[d.x >> BSHIFT], 1);
            atomicAdd(&lcnt[d.y >> BSHIFT], 1);
            atomicAdd(&lcnt[d.z >> BSHIFT], 1);
            atomicAdd(&lcnt[d.w >> BSHIFT], 1);
        }
        for (i = start + ((lim - start) & ~3) + t; i < lim; i += TPB)
            atomicAdd(&lcnt[dst[i] >> BSHIFT], 1);
        __syncthreads();
        for (int j = t; j < NB; j += TPB) cnt[hb * NB + j] = lcnt[j];
        return;
    }

    // ---- gemm1 part (unchanged, known-good) ----
    const int rbase = blockIdx.x * 64;
    const int rows = min(64, N - rbase);

    const float4* w4 = reinterpret_cast<const float4*>(W1);
    for (int i = t; i < 2048; i += TPB) {
        float4 u = w4[i];
        int o = i * 4;
        w1s[o+0] = u.x; w1s[o+1] = u.y; w1s[o+2] = u.z; w1s[o+3] = u.w;
    }
    if (t < 64) b1s[t] = b1[t];

    const float4* x4 = reinterpret_cast<const float4*>(x);
    for (int i = t; i < rows * 32; i += TPB) {
        float4 u = x4[(size_t)rbase * 32 + i];
        int row = i >> 5, kk = (i & 31) * 4;
        float* p = &xs[row * 132 + kk];
        p[0] = u.x; p[1] = u.y; p[2] = u.z; p[3] = u.w;
    }
    __syncthreads();

    const int row = t >> 2, cg = t & 3;
    if (row < rows) {
        float acc[16];
        #pragma unroll
        for (int c = 0; c < 16; c++) acc[c] = b1s[cg*16 + c];
        const float* xr = &xs[row * 132];
        #pragma unroll 4
        for (int k = 0; k < 128; k++) {
            float a = xr[k];
            const float* wp = &w1s[k*64 + cg*16];
            #pragma unroll
            for (int c = 0; c < 16; c++) acc[c] = fmaf(a, wp[c], acc[c]);
        }
        union { unsigned int u[8]; uint4 v[2]; } pk;
        #pragma unroll
        for (int j = 0; j < 8; j++)
            pk.u[j] = (unsigned int)f2bf(acc[2*j]) | ((unsigned int)f2bf(acc[2*j+1]) << 16);
        uint4* xo = reinterpret_cast<uint4*>(xlb + (size_t)(rbase + row) * 32 + cg * 8);
        xo[0] = pk.v[0];
        xo[1] = pk.v[1];
    }
}

// ---------------- K3a: per-bucket column scan of cnt -> seg + totals ----------------
// block r: exclusive scan of cnt[0..255][r]; seg[r*256+t]; totals[r]=column sum
__global__ __launch_bounds__(TPB) void k_colscan(
    const int* __restrict__ cnt, int* __restrict__ seg, int* __restrict__ totals, int NB)
{
    __shared__ int wsum[4];
    const int r = blockIdx.x;
    const int t = threadIdx.x;
    const int lane = t & 63, wid = t >> 6;
    int v = cnt[t * NB + r];
    int incl = v;
    for (int d = 1; d < 64; d <<= 1) {
        int n = __shfl_up(incl, d);
        if (lane >= d) incl += n;
    }
    if (lane == 63) wsum[wid] = incl;
    __syncthreads();
    int woff = 0;
    for (int w = 0; w < wid; w++) woff += wsum[w];
    int excl = woff + incl - v;
    seg[r * 256 + t] = excl;
    if (t == TPB - 1) totals[r] = excl + v;
}

// ---------------- K3b: exclusive scan of totals -> bucketBase (one wave) ----------------
__global__ void k_bucketbase(const int* __restrict__ totals, int* __restrict__ bb, int NB, int E)
{
    const int lane = threadIdx.x & 63;
    int carry = 0;
    for (int it = 0; it * 64 < NB; ++it) {
        int idx = it * 64 + lane;
        int v = (idx < NB) ? totals[idx] : 0;
        int incl = v;
        for (int d = 1; d < 64; d <<= 1) {
            int n = __shfl_up(incl, d);
            if (lane >= d) incl += n;
        }
        if (idx < NB) bb[idx] = carry + incl - v;
        carry += __shfl(incl, 63);
    }
    if (lane == 0) bb[NB] = E;
}

// ---------------- K4: bin edges into block-private (writer,bucket) segments ----------------
// Record = (src << BSHIFT) | dst_local  (src<2^17, dst_local<128 -> 24 bits)
__global__ __launch_bounds__(TPB) void k_fillbin(
    const int* __restrict__ ei, const int* __restrict__ seg, const int* __restrict__ bb,
    unsigned int* __restrict__ recs, int E, int NB, int CH)
{
    __shared__ int lcur[1024];
    const int blk = blockIdx.x;
    const int t = threadIdx.x;
    for (int j = t; j < NB; j += TPB)
        lcur[j] = bb[j] + seg[j * 256 + blk];
    __syncthreads();

    const int start = blk * CH;
    const int lim = min(E, start + CH);
    const int* src = ei;
    const int* dst = ei + E;
    int i = start + t * 4;
    for (; i + 3 < lim; i += TPB * 4) {
        vint4 d = __builtin_nontemporal_load(reinterpret_cast<const vint4*>(dst + i));
        vint4 s = __builtin_nontemporal_load(reinterpret_cast<const vint4*>(src + i));
        int p0 = atomicAdd(&lcur[d.x >> BSHIFT], 1);
        int p1 = atomicAdd(&lcur[d.y >> BSHIFT], 1);
        int p2 = atomicAdd(&lcur[d.z >> BSHIFT], 1);
        int p3 = atomicAdd(&lcur[d.w >> BSHIFT], 1);
        recs[p0] = ((unsigned int)s.x << BSHIFT) | (unsigned int)(d.x & (BNODES-1));
        recs[p1] = ((unsigned int)s.y << BSHIFT) | (unsigned int)(d.y & (BNODES-1));
        recs[p2] = ((unsigned int)s.z << BSHIFT) | (unsigned int)(d.z & (BNODES-1));
        recs[p3] = ((unsigned int)s.w << BSHIFT) | (unsigned int)(d.w & (BNODES-1));
    }
    for (i = start + ((lim - start) & ~3) + t; i < lim; i += TPB) {
        int d = dst[i];
        int p = atomicAdd(&lcur[d >> BSHIFT], 1);
        recs[p] = ((unsigned int)src[i] << BSHIFT) | (unsigned int)(d & (BNODES-1));
    }
}

// ---------------- K5: per-bucket LDS aggregation + self-loop + ReLU + GEMM2 ----------------
// block r: agg[128][64] f32 in LDS; stream contiguous records; wave-cooperative
// row gather (lane = feature, word = lane>>1 -> 128 B coalesced); ds_add_f32
// (bank = feature&31, 2 lanes/bank = free).
__global__ __launch_bounds__(TPB) void k_aggb(
    const unsigned int* __restrict__ xlb,   // [N,32] u32 bf16-pairs
    const unsigned int* __restrict__ recs,
    const int* __restrict__ bb,
    const float* __restrict__ W2, const float* __restrict__ b2,
    float* __restrict__ out, int N, int NB)
{
    __shared__ float agg[BNODES * 64];   // 32 KB
    __shared__ float w2s[64 * 32];       // 8 KB
    __shared__ float b2s[32];

    const int r = blockIdx.x;
    const int t = threadIdx.x;
    const int lane = t & 63, wid = t >> 6;

    for (int i = t; i < BNODES * 64; i += TPB) agg[i] = 0.f;
    const float4* w4 = reinterpret_cast<const float4*>(W2);
    for (int i = t; i < 512; i += TPB) {
        float4 u = w4[i];
        int o = i * 4;
        w2s[o+0] = u.x; w2s[o+1] = u.y; w2s[o+2] = u.z; w2s[o+3] = u.w;
    }
    if (t < 32) b2s[t] = b2[t];
    __syncthreads();

    const int bb0 = bb[r], bb1 = bb[r + 1];
    const int cr = bb1 - bb0;
    const int word = lane >> 1;
    for (int base = wid * 64; base < cr; base += 4 * 64) {
        int idx = bb0 + base + lane;
        unsigned int rec = recs[min(idx, bb1 - 1)];
        int lim = min(64, cr - base);
        int j = 0;
        for (; j + 4 <= lim; j += 4) {
            unsigned int r0 = __shfl((int)rec, j+0);
            unsigned int r1 = __shfl((int)rec, j+1);
            unsigned int r2 = __shfl((int)rec, j+2);
            unsigned int r3 = __shfl((int)rec, j+3);
            unsigned int w0 = xlb[(r0 >> BSHIFT) * 32 + word];
            unsigned int w1 = xlb[(r1 >> BSHIFT) * 32 + word];
            unsigned int w2 = xlb[(r2 >> BSHIFT) * 32 + word];
            unsigned int w3 = xlb[(r3 >> BSHIFT) * 32 + word];
            float v0 = (lane & 1) ? bfhi(w0) : bflo(w0);
            float v1 = (lane & 1) ? bfhi(w1) : bflo(w1);
            float v2 = (lane & 1) ? bfhi(w2) : bflo(w2);
            float v3 = (lane & 1) ? bfhi(w3) : bflo(w3);
            atomicAdd(&agg[(int)(r0 & (BNODES-1)) * 64 + lane], v0);
            atomicAdd(&agg[(int)(r1 & (BNODES-1)) * 64 + lane], v1);
            atomicAdd(&agg[(int)(r2 & (BNODES-1)) * 64 + lane], v2);
            atomicAdd(&agg[(int)(r3 & (BNODES-1)) * 64 + lane], v3);
        }
        for (; j < lim; ++j) {
            unsigned int rj = __shfl((int)rec, j);
            unsigned int wd = xlb[(rj >> BSHIFT) * 32 + word];
            float v = (lane & 1) ? bfhi(wd) : bflo(wd);
            atomicAdd(&agg[(int)(rj & (BNODES-1)) * 64 + lane], v);
        }
    }
    __syncthreads();

    // self-loop + relu
    for (int idx = t; idx < BNODES * 32; idx += TPB) {
        int n = idx >> 5, w = idx & 31;
        int node = r * BNODES + n;
        if (node < N) {
            unsigned int wd = xlb[(size_t)node * 32 + w];
            float a0 = agg[n * 64 + 2*w    ] + bflo(wd);
            float a1 = agg[n * 64 + 2*w + 1] + bfhi(wd);
            agg[n * 64 + 2*w    ] = fmaxf(a0, 0.f);
            agg[n * 64 + 2*w + 1] = fmaxf(a1, 0.f);
        }
    }
    __syncthreads();

    // gemm2: 256 threads -> c = t&31, node group t>>5 (16 nodes each)
    const int c = t & 31, n0 = t >> 5;
    #pragma unroll 4
    for (int m = 0; m < 16; ++m) {
        int n = n0 * 16 + m;
        int node = r * BNODES + n;
        if (node >= N) break;
        float o = b2s[c];
        const float* ar = &agg[n * 64];
        #pragma unroll
        for (int kk = 0; kk < 64; kk++)
            o = fmaf(ar[kk], w2s[kk * 32 + c], o);
        out[(size_t)node * 32 + c] = o;
    }
}

extern "C" void kernel_launch(void* const* d_in, const int* in_sizes, int n_in,
                              void* d_out, int out_size, void* d_ws, size_t ws_size,
                              hipStream_t stream) {
    const float* x  = (const float*)d_in[0];
    const int*   ei = (const int*)d_in[1];
    const float* W1 = (const float*)d_in[2];
    const float* b1 = (const float*)d_in[3];
    const float* W2 = (const float*)d_in[4];
    const float* b2 = (const float*)d_in[5];
    float* out = (float*)d_out;

    const int N = in_sizes[0] / 128;
    const int E = in_sizes[1] / 2;
    const int NB = (N + BNODES - 1) >> BSHIFT;                 // 782
    const int CH = (((E + NWRITERS - 1) / NWRITERS) + 3) & ~3; // writer chunk, mult of 4

    char* w = (char*)d_ws;
    unsigned int* xlb = (unsigned int*)w;   w += (size_t)N * 32 * 4;          // 12.8 MB
    int* cnt    = (int*)w;                  w += (size_t)NWRITERS * NB * 4;   // 800 KB
    int* seg    = (int*)w;                  w += (size_t)NB * NWRITERS * 4;   // 800 KB
    int* totals = (int*)w;                  w += ((size_t)NB * 4 + 15) & ~15ull;
    int* bbase  = (int*)w;                  w += ((size_t)(NB + 1) * 4 + 15) & ~15ull;
    unsigned int* recs = (unsigned int*)w;  // E*4 = 6.4 MB

    const int nbG = (N + 63) / 64;   // gemm1 blocks

    hipLaunchKernelGGL(k_gemm1_hist, dim3(nbG + NWRITERS), dim3(TPB), 0, stream,
                       x, W1, b1, xlb, ei, cnt, N, E, NB, CH, nbG);
    hipLaunchKernelGGL(k_colscan, dim3(NB), dim3(TPB), 0, stream, cnt, seg, totals, NB);
    hipLaunchKernelGGL(k_bucketbase, dim3(1), dim3(64), 0, stream, totals, bbase, NB, E);
    hipLaunchKernelGGL(k_fillbin, dim3(NWRITERS), dim3(TPB), 0, stream,
                       ei, seg, bbase, recs, E, NB, CH);
    hipLaunchKernelGGL(k_aggb, dim3(NB), dim3(TPB), 0, stream,
                       xlb, recs, bbase, W2, b2, out, N, NB);
}

// Round 9
// 168.742 us; speedup vs baseline: 4.7788x; 4.7788x over previous
//
#include <hip/hip_runtime.h>
#include <hip/hip_bf16.h>

#define TPB 256
#define BSHIFT 7                 // 128 nodes per bucket
#define BNODES (1 << BSHIFT)
#define NWRITERS 256             // edge-chunk writer blocks

typedef int vint4 __attribute__((ext_vector_type(4)));

// f32 -> bf16 bits, RNE
__device__ __forceinline__ unsigned short f2bf(float f) {
    unsigned int u = __float_as_uint(f);
    u += 0x7fffu + ((u >> 16) & 1u);
    return (unsigned short)(u >> 16);
}
__device__ __forceinline__ float bflo(unsigned int u) { return __uint_as_float(u << 16); }
__device__ __forceinline__ float bfhi(unsigned int u) { return __uint_as_float(u & 0xffff0000u); }

// ---- K1: fused [hist: per-writer bucket counts] + [gemm1: xl = x@W1+b1 -> bf16] ----
// hist blocks FIRST (blockIdx < NWRITERS) so they overlap gemm1 blocks.
// cnt written TRANSPOSED: cntT[bucket*NWRITERS + writer] so k_colscan reads coalesce.
__global__ __launch_bounds__(TPB) void k_gemm1_hist(
    const float* __restrict__ x, const float* __restrict__ W1, const float* __restrict__ b1,
    unsigned int* __restrict__ xlb,
    const int* __restrict__ ei, int* __restrict__ cntT,
    int N, int E, int NB, int CH)
{
    __shared__ float w1s[128 * 64];
    __shared__ float xs[64 * 132];
    __shared__ float b1s[64];
    __shared__ int   lcnt[1024];

    const int t = threadIdx.x;

    if ((int)blockIdx.x < NWRITERS) {
        const int hb = blockIdx.x;
        const int start = hb * CH;
        const int lim = min(E, start + CH);
        for (int j = t; j < NB; j += TPB) lcnt[j] = 0;
        __syncthreads();
        const int* dst = ei + E;
        int i = start + t * 4;
        for (; i + 3 < lim; i += TPB * 4) {
            vint4 d = __builtin_nontemporal_load(reinterpret_cast<const vint4*>(dst + i));
            atomicAdd(&lcnt[d.x >> BSHIFT], 1);
            atomicAdd(&lcnt[d.y >> BSHIFT], 1);
            atomicAdd(&lcnt[d.z >> BSHIFT], 1);
            atomicAdd(&lcnt[d.w >> BSHIFT], 1);
        }
        for (i = start + ((lim - start) & ~3) + t; i < lim; i += TPB)
            atomicAdd(&lcnt[dst[i] >> BSHIFT], 1);
        __syncthreads();
        for (int j = t; j < NB; j += TPB) cntT[j * NWRITERS + hb] = lcnt[j];
        return;
    }

    // ---- gemm1 part ----
    const int rbase = (blockIdx.x - NWRITERS) * 64;
    const int rows = min(64, N - rbase);

    const float4* w4 = reinterpret_cast<const float4*>(W1);
    for (int i = t; i < 2048; i += TPB) {
        float4 u = w4[i];
        int o = i * 4;
        w1s[o+0] = u.x; w1s[o+1] = u.y; w1s[o+2] = u.z; w1s[o+3] = u.w;
    }
    if (t < 64) b1s[t] = b1[t];

    const float4* x4 = reinterpret_cast<const float4*>(x);
    for (int i = t; i < rows * 32; i += TPB) {
        float4 u = x4[(size_t)rbase * 32 + i];
        int row = i >> 5, kk = (i & 31) * 4;
        float* p = &xs[row * 132 + kk];
        p[0] = u.x; p[1] = u.y; p[2] = u.z; p[3] = u.w;
    }
    __syncthreads();

    const int row = t >> 2, cg = t & 3;
    if (row < rows) {
        float acc[16];
        #pragma unroll
        for (int c = 0; c < 16; c++) acc[c] = b1s[cg*16 + c];
        const float* xr = &xs[row * 132];
        #pragma unroll 4
        for (int k = 0; k < 128; k++) {
            float a = xr[k];
            const float* wp = &w1s[k*64 + cg*16];
            #pragma unroll
            for (int c = 0; c < 16; c++) acc[c] = fmaf(a, wp[c], acc[c]);
        }
        union { unsigned int u[8]; uint4 v[2]; } pk;
        #pragma unroll
        for (int j = 0; j < 8; j++)
            pk.u[j] = (unsigned int)f2bf(acc[2*j]) | ((unsigned int)f2bf(acc[2*j+1]) << 16);
        uint4* xo = reinterpret_cast<uint4*>(xlb + (size_t)(rbase + row) * 32 + cg * 8);
        xo[0] = pk.v[0];
        xo[1] = pk.v[1];
    }
}

// ---- K2: per-bucket scan of writer counts -> segT (transposed) + totals ----
__global__ __launch_bounds__(TPB) void k_colscan(
    const int* __restrict__ cntT, int* __restrict__ segT, int* __restrict__ totals, int NB)
{
    __shared__ int wsum[4];
    const int r = blockIdx.x;
    const int t = threadIdx.x;
    const int lane = t & 63, wid = t >> 6;
    int v = cntT[r * NWRITERS + t];      // coalesced
    int incl = v;
    for (int d = 1; d < 64; d <<= 1) {
        int n = __shfl_up(incl, d);
        if (lane >= d) incl += n;
    }
    if (lane == 63) wsum[wid] = incl;
    __syncthreads();
    int woff = 0;
    for (int w = 0; w < wid; w++) woff += wsum[w];
    int excl = woff + incl - v;
    segT[r * NWRITERS + t] = excl;       // coalesced
    if (t == TPB - 1) totals[r] = excl + v;
}

// ---- K3: exclusive scan of bucket totals -> bucket base (one wave) ----
__global__ void k_bucketbase(const int* __restrict__ totals, int* __restrict__ bb, int NB, int E)
{
    const int lane = threadIdx.x & 63;
    int carry = 0;
    for (int it = 0; it * 64 < NB; ++it) {
        int idx = it * 64 + lane;
        int v = (idx < NB) ? totals[idx] : 0;
        int incl = v;
        for (int d = 1; d < 64; d <<= 1) {
            int n = __shfl_up(incl, d);
            if (lane >= d) incl += n;
        }
        if (idx < NB) bb[idx] = carry + incl - v;
        carry += __shfl(incl, 63);
    }
    if (lane == 0) bb[NB] = E;
}

// ---- K4: bin edges into block-private (writer,bucket) segments ----
// Record = (src << BSHIFT) | dst_local  (17 + 7 = 24 bits)
__global__ __launch_bounds__(TPB) void k_fillbin(
    const int* __restrict__ ei, const int* __restrict__ segT, const int* __restrict__ bb,
    unsigned int* __restrict__ recs, int E, int NB, int CH)
{
    __shared__ int lcur[1024];
    const int blk = blockIdx.x;
    const int t = threadIdx.x;
    for (int j = t; j < NB; j += TPB)
        lcur[j] = bb[j] + segT[j * NWRITERS + blk];
    __syncthreads();

    const int start = blk * CH;
    const int lim = min(E, start + CH);
    const int* src = ei;
    const int* dst = ei + E;
    int i = start + t * 4;
    for (; i + 3 < lim; i += TPB * 4) {
        vint4 d = __builtin_nontemporal_load(reinterpret_cast<const vint4*>(dst + i));
        vint4 s = __builtin_nontemporal_load(reinterpret_cast<const vint4*>(src + i));
        int p0 = atomicAdd(&lcur[d.x >> BSHIFT], 1);
        int p1 = atomicAdd(&lcur[d.y >> BSHIFT], 1);
        int p2 = atomicAdd(&lcur[d.z >> BSHIFT], 1);
        int p3 = atomicAdd(&lcur[d.w >> BSHIFT], 1);
        recs[p0] = ((unsigned int)s.x << BSHIFT) | (unsigned int)(d.x & (BNODES-1));
        recs[p1] = ((unsigned int)s.y << BSHIFT) | (unsigned int)(d.y & (BNODES-1));
        recs[p2] = ((unsigned int)s.z << BSHIFT) | (unsigned int)(d.z & (BNODES-1));
        recs[p3] = ((unsigned int)s.w << BSHIFT) | (unsigned int)(d.w & (BNODES-1));
    }
    for (i = start + ((lim - start) & ~3) + t; i < lim; i += TPB) {
        int d = dst[i];
        int p = atomicAdd(&lcur[d >> BSHIFT], 1);
        recs[p] = ((unsigned int)src[i] << BSHIFT) | (unsigned int)(d & (BNODES-1));
    }
}

// ---- K5: per-bucket local counting sort -> node-sorted esrc + global off ----
// Block r: two passes over its ~2K-record segment (8 KB, L2-hot).
__global__ __launch_bounds__(TPB) void k_bsort(
    const unsigned int* __restrict__ recs, const int* __restrict__ bb,
    int* __restrict__ esrc, int* __restrict__ off, int N, int NB, int E)
{
    __shared__ int h[BNODES];
    __shared__ int cur[BNODES];
    __shared__ int ws2[2];

    const int r = blockIdx.x;
    const int t = threadIdx.x;
    const int bb0 = bb[r], bb1 = bb[r + 1];

    if (t < BNODES) h[t] = 0;
    __syncthreads();
    for (int i = bb0 + t; i < bb1; i += TPB)
        atomicAdd(&h[recs[i] & (BNODES - 1)], 1);
    __syncthreads();

    // exclusive scan of 128 counters (2 waves)
    int v = 0, incl = 0;
    const int lane = t & 63, w = t >> 6;
    if (t < BNODES) {
        v = h[t];
        incl = v;
        for (int d = 1; d < 64; d <<= 1) {
            int n = __shfl_up(incl, d);
            if (lane >= d) incl += n;
        }
        if (lane == 63) ws2[w] = incl;
    }
    __syncthreads();
    if (t < BNODES) {
        int excl = incl - v + (w ? ws2[0] : 0);
        cur[t] = bb0 + excl;
        int node = r * BNODES + t;
        if (node < N) off[node] = bb0 + excl;
    }
    if (r == NB - 1 && t == 0) off[N] = E;
    __syncthreads();

    for (int i = bb0 + t; i < bb1; i += TPB) {
        unsigned int rec = recs[i];
        int p = atomicAdd(&cur[rec & (BNODES - 1)], 1);
        esrc[p] = (int)(rec >> BSHIFT);
    }
}

// ---- K6: aggregate (bf16 gather) + ReLU + GEMM2 fused (round-7 proven) ----
#define AGG_BLOCKS 2048
__global__ __launch_bounds__(TPB) void k_agg(
    const unsigned int* __restrict__ xlb,  // [N,32] u32 (bf16 pairs)
    const int* __restrict__ off,           // [N+1]
    const int* __restrict__ esrc,          // [E]
    const float* __restrict__ W2,          // [64,32]
    const float* __restrict__ b2,          // [32]
    float* __restrict__ out, int N)
{
    __shared__ float w2s[64 * 32];
    __shared__ float b2s[32];
    __shared__ float arow[4][68];

    const int t = threadIdx.x;
    const float4* w4 = reinterpret_cast<const float4*>(W2);
    for (int i = t; i < 512; i += TPB) {
        float4 u = w4[i];
        int o = i * 4;
        w2s[o+0] = u.x; w2s[o+1] = u.y; w2s[o+2] = u.z; w2s[o+3] = u.w;
    }
    if (t < 32) b2s[t] = b2[t];
    __syncthreads();

    const int wid = t >> 6, lane = t & 63;
    const int slot = lane >> 3, b = lane & 7;
    const int c = lane & 31, h = lane >> 5;
    const uint4* xb4 = reinterpret_cast<const uint4*>(xlb);

    for (int node = blockIdx.x * 4 + wid; node < N; node += gridDim.x * 4) {
        const int beg = off[node], end = off[node + 1];
        float a0=0.f,a1=0.f,a2=0.f,a3=0.f,a4=0.f,a5=0.f,a6=0.f,a7=0.f;
        int e = beg + slot;
        for (; e + 8 < end; e += 16) {
            int s0 = esrc[e];
            int s1 = esrc[e + 8];
            uint4 v0 = xb4[(size_t)s0 * 8 + b];
            uint4 v1 = xb4[(size_t)s1 * 8 + b];
            a0 += bflo(v0.x); a1 += bfhi(v0.x);
            a2 += bflo(v0.y); a3 += bfhi(v0.y);
            a4 += bflo(v0.z); a5 += bfhi(v0.z);
            a6 += bflo(v0.w); a7 += bfhi(v0.w);
            a0 += bflo(v1.x); a1 += bfhi(v1.x);
            a2 += bflo(v1.y); a3 += bfhi(v1.y);
            a4 += bflo(v1.z); a5 += bfhi(v1.z);
            a6 += bflo(v1.w); a7 += bfhi(v1.w);
        }
        if (e < end) {
            int s = esrc[e];
            uint4 v = xb4[(size_t)s * 8 + b];
            a0 += bflo(v.x); a1 += bfhi(v.x);
            a2 += bflo(v.y); a3 += bfhi(v.y);
            a4 += bflo(v.z); a5 += bfhi(v.z);
            a6 += bflo(v.w); a7 += bfhi(v.w);
        }
        #pragma unroll
        for (int d = 8; d <= 32; d <<= 1) {
            a0 += __shfl_xor(a0, d); a1 += __shfl_xor(a1, d);
            a2 += __shfl_xor(a2, d); a3 += __shfl_xor(a3, d);
            a4 += __shfl_xor(a4, d); a5 += __shfl_xor(a5, d);
            a6 += __shfl_xor(a6, d); a7 += __shfl_xor(a7, d);
        }
        if (slot == 0) {
            uint4 sv = xb4[(size_t)node * 8 + b];
            float* p = &arow[wid][b * 8];
            p[0] = fmaxf(a0 + bflo(sv.x), 0.f);
            p[1] = fmaxf(a1 + bfhi(sv.x), 0.f);
            p[2] = fmaxf(a2 + bflo(sv.y), 0.f);
            p[3] = fmaxf(a3 + bfhi(sv.y), 0.f);
            p[4] = fmaxf(a4 + bflo(sv.z), 0.f);
            p[5] = fmaxf(a5 + bfhi(sv.z), 0.f);
            p[6] = fmaxf(a6 + bflo(sv.w), 0.f);
            p[7] = fmaxf(a7 + bfhi(sv.w), 0.f);
        }
        float o = 0.f;
        const float* ar = &arow[wid][h * 32];
        const float* wp = &w2s[h * 32 * 32 + c];
        #pragma unroll
        for (int kk = 0; kk < 32; kk++)
            o = fmaf(ar[kk], wp[kk * 32], o);
        o += __shfl_xor(o, 32);
        if (h == 0) out[(size_t)node * 32 + c] = o + b2s[c];
    }
}

extern "C" void kernel_launch(void* const* d_in, const int* in_sizes, int n_in,
                              void* d_out, int out_size, void* d_ws, size_t ws_size,
                              hipStream_t stream) {
    const float* x  = (const float*)d_in[0];
    const int*   ei = (const int*)d_in[1];
    const float* W1 = (const float*)d_in[2];
    const float* b1 = (const float*)d_in[3];
    const float* W2 = (const float*)d_in[4];
    const float* b2 = (const float*)d_in[5];
    float* out = (float*)d_out;

    const int N = in_sizes[0] / 128;
    const int E = in_sizes[1] / 2;
    const int NB = (N + BNODES - 1) >> BSHIFT;                 // 782
    const int CH = (((E + NWRITERS - 1) / NWRITERS) + 3) & ~3; // writer chunk, mult of 4

    char* w = (char*)d_ws;
    unsigned int* xlb = (unsigned int*)w;   w += (size_t)N * 32 * 4;          // 12.8 MB
    int* cntT   = (int*)w;                  w += (size_t)NB * NWRITERS * 4;   // 800 KB
    int* segT   = (int*)w;                  w += (size_t)NB * NWRITERS * 4;   // 800 KB
    int* totals = (int*)w;                  w += ((size_t)NB * 4 + 15) & ~15ull;
    int* bbase  = (int*)w;                  w += ((size_t)(NB + 1) * 4 + 15) & ~15ull;
    int* off    = (int*)w;                  w += ((size_t)(N + 1) * 4 + 15) & ~15ull;
    unsigned int* recs = (unsigned int*)w;  w += (size_t)E * 4;               // 6.4 MB
    int* esrc   = (int*)w;                  // 6.4 MB

    const int nbG = (N + 63) / 64;   // gemm1 blocks

    hipLaunchKernelGGL(k_gemm1_hist, dim3(NWRITERS + nbG), dim3(TPB), 0, stream,
                       x, W1, b1, xlb, ei, cntT, N, E, NB, CH);
    hipLaunchKernelGGL(k_colscan, dim3(NB), dim3(TPB), 0, stream, cntT, segT, totals, NB);
    hipLaunchKernelGGL(k_bucketbase, dim3(1), dim3(64), 0, stream, totals, bbase, NB, E);
    hipLaunchKernelGGL(k_fillbin, dim3(NWRITERS), dim3(TPB), 0, stream,
                       ei, segT, bbase, recs, E, NB, CH);
    hipLaunchKernelGGL(k_bsort, dim3(NB), dim3(TPB), 0, stream,
                       recs, bbase, esrc, off, N, NB, E);
    hipLaunchKernelGGL(k_agg, dim3(AGG_BLOCKS), dim3(TPB), 0, stream,
                       xlb, off, esrc, W2, b2, out, N);
}

// Round 10
// 144.721 us; speedup vs baseline: 5.5719x; 1.1660x over previous
//
#include <hip/hip_runtime.h>
#include <hip/hip_bf16.h>

#define TPB 256
#define BSHIFT 7                 // 128 nodes per bucket
#define BNODES (1 << BSHIFT)
#define NWRITERS 256             // edge-chunk writer blocks

typedef int vint4 __attribute__((ext_vector_type(4)));
typedef __attribute__((ext_vector_type(8))) short short8v;   // 8 bf16 (4 VGPRs)
typedef __attribute__((ext_vector_type(4))) float f32x4;

// f32 -> bf16 bits, RNE
__device__ __forceinline__ unsigned short f2bf(float f) {
    unsigned int u = __float_as_uint(f);
    u += 0x7fffu + ((u >> 16) & 1u);
    return (unsigned short)(u >> 16);
}
__device__ __forceinline__ float bflo(unsigned int u) { return __uint_as_float(u << 16); }
__device__ __forceinline__ float bfhi(unsigned int u) { return __uint_as_float(u & 0xffff0000u); }

// ---- K1: fused [hist: per-writer bucket counts] + [gemm1 MFMA: xlb = bf16(x@W1+b1)] ----
__global__ __launch_bounds__(TPB) void k_gemm1_hist(
    const float* __restrict__ x, const float* __restrict__ W1, const float* __restrict__ b1,
    unsigned int* __restrict__ xlb,
    const int* __restrict__ ei, int* __restrict__ cntT,
    int N, int E, int NB, int CH)
{
    __shared__ unsigned short wT[64 * 136];   // W1^T bf16, row stride 136 (pad: 2-way = free)
    __shared__ float b1s[64];
    __shared__ int   lcnt[1024];

    const int t = threadIdx.x;

    if ((int)blockIdx.x < NWRITERS) {
        // ---- histogram: writer block counts its private edge chunk into buckets ----
        const int hb = blockIdx.x;
        const int start = hb * CH;
        const int lim = min(E, start + CH);
        for (int j = t; j < NB; j += TPB) lcnt[j] = 0;
        __syncthreads();
        const int* dst = ei + E;
        int i = start + t * 4;
        for (; i + 3 < lim; i += TPB * 4) {
            vint4 d = __builtin_nontemporal_load(reinterpret_cast<const vint4*>(dst + i));
            atomicAdd(&lcnt[d.x >> BSHIFT], 1);
            atomicAdd(&lcnt[d.y >> BSHIFT], 1);
            atomicAdd(&lcnt[d.z >> BSHIFT], 1);
            atomicAdd(&lcnt[d.w >> BSHIFT], 1);
        }
        for (i = start + ((lim - start) & ~3) + t; i < lim; i += TPB)
            atomicAdd(&lcnt[dst[i] >> BSHIFT], 1);
        __syncthreads();
        for (int j = t; j < NB; j += TPB) cntT[j * NWRITERS + hb] = lcnt[j];
        return;
    }

    // ---- gemm1 MFMA: 4 waves x 16 rows = 64 rows/block ----
    // stage W1^T as bf16: threads read W1[k][cw..cw+3] float4 coalesced
    for (int i = t; i < 2048; i += TPB) {
        int k = i >> 4, cw = (i & 15) * 4;
        float4 u = reinterpret_cast<const float4*>(W1)[i];
        wT[(cw + 0) * 136 + k] = f2bf(u.x);
        wT[(cw + 1) * 136 + k] = f2bf(u.y);
        wT[(cw + 2) * 136 + k] = f2bf(u.z);
        wT[(cw + 3) * 136 + k] = f2bf(u.w);
    }
    if (t < 64) b1s[t] = b1[t];
    __syncthreads();

    const int l = t & 63, wid = t >> 6;
    const int cl = l & 15, kg = l >> 4;
    const int rw = ((int)blockIdx.x - NWRITERS) * 64 + wid * 16;
    if (rw >= N) return;
    const int r = rw + cl;                    // A row for this lane (N%16==0 path; stores guarded)

    const float4* xp4 = reinterpret_cast<const float4*>(x) + ((size_t)min(r, N - 1) * 32 + kg * 2);

    f32x4 acc[4] = {};
    #pragma unroll
    for (int kt = 0; kt < 4; ++kt) {
        float4 fA = xp4[kt * 8];
        float4 fB = xp4[kt * 8 + 1];
        short8v a;
        a[0] = (short)f2bf(fA.x); a[1] = (short)f2bf(fA.y);
        a[2] = (short)f2bf(fA.z); a[3] = (short)f2bf(fA.w);
        a[4] = (short)f2bf(fB.x); a[5] = (short)f2bf(fB.y);
        a[6] = (short)f2bf(fB.z); a[7] = (short)f2bf(fB.w);
        #pragma unroll
        for (int ct = 0; ct < 4; ++ct) {
            short8v b = *reinterpret_cast<const short8v*>(
                &wT[(ct * 16 + cl) * 136 + kt * 32 + kg * 8]);
            acc[ct] = __builtin_amdgcn_mfma_f32_16x16x32_bf16(a, b, acc[ct], 0, 0, 0);
        }
    }

    // C store: col=lane&15, row=(lane>>4)*4+reg; pack bf16 pairs via shfl_xor(1)
    #pragma unroll
    for (int ct = 0; ct < 4; ++ct) {
        #pragma unroll
        for (int reg = 0; reg < 4; ++reg) {
            int row = rw + kg * 4 + reg;
            float v = acc[ct][reg] + b1s[ct * 16 + cl];
            unsigned int m = (unsigned int)f2bf(v);
            unsigned int p = (unsigned int)__shfl_xor((int)m, 1);
            if (!(l & 1) && row < N)
                xlb[(size_t)row * 32 + ct * 8 + (cl >> 1)] = m | (p << 16);
        }
    }
}

// ---- K2: per-bucket scan of writer counts -> segT (transposed) + totals ----
__global__ __launch_bounds__(TPB) void k_colscan(
    const int* __restrict__ cntT, int* __restrict__ segT, int* __restrict__ totals, int NB)
{
    __shared__ int wsum[4];
    const int r = blockIdx.x;
    const int t = threadIdx.x;
    const int lane = t & 63, wid = t >> 6;
    int v = cntT[r * NWRITERS + t];
    int incl = v;
    for (int d = 1; d < 64; d <<= 1) {
        int n = __shfl_up(incl, d);
        if (lane >= d) incl += n;
    }
    if (lane == 63) wsum[wid] = incl;
    __syncthreads();
    int woff = 0;
    for (int w = 0; w < wid; w++) woff += wsum[w];
    int excl = woff + incl - v;
    segT[r * NWRITERS + t] = excl;
    if (t == TPB - 1) totals[r] = excl + v;
}

// ---- K3: exclusive scan of bucket totals -> bucket base (one wave) ----
__global__ void k_bucketbase(const int* __restrict__ totals, int* __restrict__ bb, int NB, int E)
{
    const int lane = threadIdx.x & 63;
    int carry = 0;
    for (int it = 0; it * 64 < NB; ++it) {
        int idx = it * 64 + lane;
        int v = (idx < NB) ? totals[idx] : 0;
        int incl = v;
        for (int d = 1; d < 64; d <<= 1) {
            int n = __shfl_up(incl, d);
            if (lane >= d) incl += n;
        }
        if (idx < NB) bb[idx] = carry + incl - v;
        carry += __shfl(incl, 63);
    }
    if (lane == 0) bb[NB] = E;
}

// ---- K4: bin edges into block-private (writer,bucket) segments ----
__global__ __launch_bounds__(TPB) void k_fillbin(
    const int* __restrict__ ei, const int* __restrict__ segT, const int* __restrict__ bb,
    unsigned int* __restrict__ recs, int E, int NB, int CH)
{
    __shared__ int lcur[1024];
    const int blk = blockIdx.x;
    const int t = threadIdx.x;
    for (int j = t; j < NB; j += TPB)
        lcur[j] = bb[j] + segT[j * NWRITERS + blk];
    __syncthreads();

    const int start = blk * CH;
    const int lim = min(E, start + CH);
    const int* src = ei;
    const int* dst = ei + E;
    int i = start + t * 4;
    for (; i + 3 < lim; i += TPB * 4) {
        vint4 d = __builtin_nontemporal_load(reinterpret_cast<const vint4*>(dst + i));
        vint4 s = __builtin_nontemporal_load(reinterpret_cast<const vint4*>(src + i));
        int p0 = atomicAdd(&lcur[d.x >> BSHIFT], 1);
        int p1 = atomicAdd(&lcur[d.y >> BSHIFT], 1);
        int p2 = atomicAdd(&lcur[d.z >> BSHIFT], 1);
        int p3 = atomicAdd(&lcur[d.w >> BSHIFT], 1);
        recs[p0] = ((unsigned int)s.x << BSHIFT) | (unsigned int)(d.x & (BNODES-1));
        recs[p1] = ((unsigned int)s.y << BSHIFT) | (unsigned int)(d.y & (BNODES-1));
        recs[p2] = ((unsigned int)s.z << BSHIFT) | (unsigned int)(d.z & (BNODES-1));
        recs[p3] = ((unsigned int)s.w << BSHIFT) | (unsigned int)(d.w & (BNODES-1));
    }
    for (i = start + ((lim - start) & ~3) + t; i < lim; i += TPB) {
        int d = dst[i];
        int p = atomicAdd(&lcur[d >> BSHIFT], 1);
        recs[p] = ((unsigned int)src[i] << BSHIFT) | (unsigned int)(d & (BNODES-1));
    }
}

// ---- K5: per-bucket counting sort -> node-sorted esrc + global off ----
__global__ __launch_bounds__(TPB) void k_bsort(
    const unsigned int* __restrict__ recs, const int* __restrict__ bb,
    int* __restrict__ esrc, int* __restrict__ off, int N, int NB, int E)
{
    __shared__ int h[BNODES];
    __shared__ int cur[BNODES];
    __shared__ int ws2[2];

    const int r = blockIdx.x;
    const int t = threadIdx.x;
    const int bb0 = bb[r], bb1 = bb[r + 1];

    if (t < BNODES) h[t] = 0;
    __syncthreads();
    for (int i = bb0 + t; i < bb1; i += TPB)
        atomicAdd(&h[recs[i] & (BNODES - 1)], 1);
    __syncthreads();

    int v = 0, incl = 0;
    const int lane = t & 63, w = t >> 6;
    if (t < BNODES) {
        v = h[t];
        incl = v;
        for (int d = 1; d < 64; d <<= 1) {
            int n = __shfl_up(incl, d);
            if (lane >= d) incl += n;
        }
        if (lane == 63) ws2[w] = incl;
    }
    __syncthreads();
    if (t < BNODES) {
        int excl = incl - v + (w ? ws2[0] : 0);
        cur[t] = bb0 + excl;
        int node = r * BNODES + t;
        if (node < N) off[node] = bb0 + excl;
    }
    if (r == NB - 1 && t == 0) off[N] = E;
    __syncthreads();

    for (int i = bb0 + t; i < bb1; i += TPB) {
        unsigned int rec = recs[i];
        int p = atomicAdd(&cur[rec & (BNODES - 1)], 1);
        esrc[p] = (int)(rec >> BSHIFT);
    }
}

// ---- K6: aggregate + ReLU + GEMM2. 4 slots x 16 lanes/edge, uint2/lane (4-deep MLP) ----
#define AGG_BLOCKS 2048
__global__ __launch_bounds__(TPB) void k_agg(
    const unsigned int* __restrict__ xlb,  // [N,32] u32 (bf16 pairs)
    const int* __restrict__ off,           // [N+1]
    const int* __restrict__ esrc,          // [E]
    const float* __restrict__ W2,          // [64,32]
    const float* __restrict__ b2,          // [32]
    float* __restrict__ out, int N)
{
    __shared__ float w2s[64 * 32];
    __shared__ float b2s[32];
    __shared__ float arow[4][68];

    const int t = threadIdx.x;
    const float4* w4 = reinterpret_cast<const float4*>(W2);
    for (int i = t; i < 512; i += TPB) {
        float4 u = w4[i];
        int o = i * 4;
        w2s[o+0] = u.x; w2s[o+1] = u.y; w2s[o+2] = u.z; w2s[o+3] = u.w;
    }
    if (t < 32) b2s[t] = b2[t];
    __syncthreads();

    const int wid = t >> 6, lane = t & 63;
    const int slot = lane >> 4, b = lane & 15;    // 4 edge slots x 16 lanes (uint2 each)
    const int c = lane & 31, h = lane >> 5;       // gemm2 mapping
    const uint2* xb2 = reinterpret_cast<const uint2*>(xlb);

    for (int node = blockIdx.x * 4 + wid; node < N; node += gridDim.x * 4) {
        const int beg = off[node], end = off[node + 1];
        float a0 = 0.f, a1 = 0.f, a2 = 0.f, a3 = 0.f;
        int e = beg + slot;
        for (; e + 12 < end; e += 16) {           // 4-deep: 4 esrc + 4 gathers in flight
            int s0 = esrc[e], s1 = esrc[e + 4], s2 = esrc[e + 8], s3 = esrc[e + 12];
            uint2 v0 = xb2[(size_t)s0 * 16 + b];
            uint2 v1 = xb2[(size_t)s1 * 16 + b];
            uint2 v2 = xb2[(size_t)s2 * 16 + b];
            uint2 v3 = xb2[(size_t)s3 * 16 + b];
            a0 += bflo(v0.x); a1 += bfhi(v0.x); a2 += bflo(v0.y); a3 += bfhi(v0.y);
            a0 += bflo(v1.x); a1 += bfhi(v1.x); a2 += bflo(v1.y); a3 += bfhi(v1.y);
            a0 += bflo(v2.x); a1 += bfhi(v2.x); a2 += bflo(v2.y); a3 += bfhi(v2.y);
            a0 += bflo(v3.x); a1 += bfhi(v3.x); a2 += bflo(v3.y); a3 += bfhi(v3.y);
        }
        for (; e < end; e += 4) {
            uint2 v = xb2[(size_t)esrc[e] * 16 + b];
            a0 += bflo(v.x); a1 += bfhi(v.x); a2 += bflo(v.y); a3 += bfhi(v.y);
        }
        // reduce across 4 slots (lane bits 4,5)
        a0 += __shfl_xor(a0, 16); a1 += __shfl_xor(a1, 16);
        a2 += __shfl_xor(a2, 16); a3 += __shfl_xor(a3, 16);
        a0 += __shfl_xor(a0, 32); a1 += __shfl_xor(a1, 32);
        a2 += __shfl_xor(a2, 32); a3 += __shfl_xor(a3, 32);
        if (slot == 0) {
            uint2 sv = xb2[(size_t)node * 16 + b];   // self-loop
            float4 w;
            w.x = fmaxf(a0 + bflo(sv.x), 0.f);
            w.y = fmaxf(a1 + bfhi(sv.x), 0.f);
            w.z = fmaxf(a2 + bflo(sv.y), 0.f);
            w.w = fmaxf(a3 + bfhi(sv.y), 0.f);
            *reinterpret_cast<float4*>(&arow[wid][b * 4]) = w;
        }
        float o = 0.f;
        const float* ar = &arow[wid][h * 32];
        const float* wp = &w2s[h * 32 * 32 + c];
        #pragma unroll
        for (int kk = 0; kk < 32; kk++)
            o = fmaf(ar[kk], wp[kk * 32], o);
        o += __shfl_xor(o, 32);
        if (h == 0) out[(size_t)node * 32 + c] = o + b2s[c];
    }
}

extern "C" void kernel_launch(void* const* d_in, const int* in_sizes, int n_in,
                              void* d_out, int out_size, void* d_ws, size_t ws_size,
                              hipStream_t stream) {
    const float* x  = (const float*)d_in[0];
    const int*   ei = (const int*)d_in[1];
    const float* W1 = (const float*)d_in[2];
    const float* b1 = (const float*)d_in[3];
    const float* W2 = (const float*)d_in[4];
    const float* b2 = (const float*)d_in[5];
    float* out = (float*)d_out;

    const int N = in_sizes[0] / 128;
    const int E = in_sizes[1] / 2;
    const int NB = (N + BNODES - 1) >> BSHIFT;
    const int CH = (((E + NWRITERS - 1) / NWRITERS) + 3) & ~3;

    char* w = (char*)d_ws;
    unsigned int* xlb = (unsigned int*)w;   w += (size_t)N * 32 * 4;          // 12.8 MB
    int* cntT   = (int*)w;                  w += (size_t)NB * NWRITERS * 4;   // 800 KB
    int* segT   = (int*)w;                  w += (size_t)NB * NWRITERS * 4;   // 800 KB
    int* totals = (int*)w;                  w += ((size_t)NB * 4 + 15) & ~15ull;
    int* bbase  = (int*)w;                  w += ((size_t)(NB + 1) * 4 + 15) & ~15ull;
    int* off    = (int*)w;                  w += ((size_t)(N + 1) * 4 + 15) & ~15ull;
    unsigned int* recs = (unsigned int*)w;  w += (size_t)E * 4;               // 6.4 MB
    int* esrc   = (int*)w;                  // 6.4 MB

    const int nbG = (N + 63) / 64;

    hipLaunchKernelGGL(k_gemm1_hist, dim3(NWRITERS + nbG), dim3(TPB), 0, stream,
                       x, W1, b1, xlb, ei, cntT, N, E, NB, CH);
    hipLaunchKernelGGL(k_colscan, dim3(NB), dim3(TPB), 0, stream, cntT, segT, totals, NB);
    hipLaunchKernelGGL(k_bucketbase, dim3(1), dim3(64), 0, stream, totals, bbase, NB, E);
    hipLaunchKernelGGL(k_fillbin, dim3(NWRITERS), dim3(TPB), 0, stream,
                       ei, segT, bbase, recs, E, NB, CH);
    hipLaunchKernelGGL(k_bsort, dim3(NB), dim3(TPB), 0, stream,
                       recs, bbase, esrc, off, N, NB, E);
    hipLaunchKernelGGL(k_agg, dim3(AGG_BLOCKS), dim3(TPB), 0, stream,
                       xlb, off, esrc, W2, b2, out, N);
}

// Round 11
// 142.690 us; speedup vs baseline: 5.6513x; 1.0142x over previous
//
#include <hip/hip_runtime.h>
#include <hip/hip_bf16.h>

#define TPB 256
#define BSHIFT 7                 // 128 nodes per bucket
#define BNODES (1 << BSHIFT)
#define NWRITERS 256             // edge-chunk writer blocks
#define CAP 4096                 // LDS record capacity per bucket (mean 2048, sd ~45)

typedef int vint4 __attribute__((ext_vector_type(4)));
typedef __attribute__((ext_vector_type(8))) short short8v;   // 8 bf16 (4 VGPRs)
typedef __attribute__((ext_vector_type(4))) float f32x4;

// f32 -> bf16 bits, RNE
__device__ __forceinline__ unsigned short f2bf(float f) {
    unsigned int u = __float_as_uint(f);
    u += 0x7fffu + ((u >> 16) & 1u);
    return (unsigned short)(u >> 16);
}
__device__ __forceinline__ float bflo(unsigned int u) { return __uint_as_float(u << 16); }
__device__ __forceinline__ float bfhi(unsigned int u) { return __uint_as_float(u & 0xffff0000u); }

// ---- K1: fused [hist: per-writer bucket counts] + [gemm1 MFMA: xlb = bf16(x@W1+b1)] ----
__global__ __launch_bounds__(TPB) void k_gemm1_hist(
    const float* __restrict__ x, const float* __restrict__ W1, const float* __restrict__ b1,
    unsigned int* __restrict__ xlb,
    const int* __restrict__ ei, int* __restrict__ cntT,
    int N, int E, int NB, int CH)
{
    __shared__ unsigned short wT[64 * 136];   // W1^T bf16, stride 136 (2-way = free)
    __shared__ float b1s[64];
    __shared__ int   lcnt[1024];

    const int t = threadIdx.x;

    if ((int)blockIdx.x < NWRITERS) {
        const int hb = blockIdx.x;
        const int start = hb * CH;
        const int lim = min(E, start + CH);
        for (int j = t; j < NB; j += TPB) lcnt[j] = 0;
        __syncthreads();
        const int* dst = ei + E;
        int i = start + t * 4;
        for (; i + 3 < lim; i += TPB * 4) {
            vint4 d = __builtin_nontemporal_load(reinterpret_cast<const vint4*>(dst + i));
            atomicAdd(&lcnt[d.x >> BSHIFT], 1);
            atomicAdd(&lcnt[d.y >> BSHIFT], 1);
            atomicAdd(&lcnt[d.z >> BSHIFT], 1);
            atomicAdd(&lcnt[d.w >> BSHIFT], 1);
        }
        for (i = start + ((lim - start) & ~3) + t; i < lim; i += TPB)
            atomicAdd(&lcnt[dst[i] >> BSHIFT], 1);
        __syncthreads();
        for (int j = t; j < NB; j += TPB) cntT[j * NWRITERS + hb] = lcnt[j];
        return;
    }

    // ---- gemm1 MFMA: 4 waves x 16 rows = 64 rows/block ----
    for (int i = t; i < 2048; i += TPB) {
        int k = i >> 4, cw = (i & 15) * 4;
        float4 u = reinterpret_cast<const float4*>(W1)[i];
        wT[(cw + 0) * 136 + k] = f2bf(u.x);
        wT[(cw + 1) * 136 + k] = f2bf(u.y);
        wT[(cw + 2) * 136 + k] = f2bf(u.z);
        wT[(cw + 3) * 136 + k] = f2bf(u.w);
    }
    if (t < 64) b1s[t] = b1[t];
    __syncthreads();

    const int l = t & 63, wid = t >> 6;
    const int cl = l & 15, kg = l >> 4;
    const int rw = ((int)blockIdx.x - NWRITERS) * 64 + wid * 16;
    if (rw >= N) return;
    const int r = rw + cl;

    const float4* xp4 = reinterpret_cast<const float4*>(x) + ((size_t)min(r, N - 1) * 32 + kg * 2);

    f32x4 acc[4] = {};
    #pragma unroll
    for (int kt = 0; kt < 4; ++kt) {
        float4 fA = xp4[kt * 8];
        float4 fB = xp4[kt * 8 + 1];
        short8v a;
        a[0] = (short)f2bf(fA.x); a[1] = (short)f2bf(fA.y);
        a[2] = (short)f2bf(fA.z); a[3] = (short)f2bf(fA.w);
        a[4] = (short)f2bf(fB.x); a[5] = (short)f2bf(fB.y);
        a[6] = (short)f2bf(fB.z); a[7] = (short)f2bf(fB.w);
        #pragma unroll
        for (int ct = 0; ct < 4; ++ct) {
            short8v b = *reinterpret_cast<const short8v*>(
                &wT[(ct * 16 + cl) * 136 + kt * 32 + kg * 8]);
            acc[ct] = __builtin_amdgcn_mfma_f32_16x16x32_bf16(a, b, acc[ct], 0, 0, 0);
        }
    }

    #pragma unroll
    for (int ct = 0; ct < 4; ++ct) {
        #pragma unroll
        for (int reg = 0; reg < 4; ++reg) {
            int row = rw + kg * 4 + reg;
            float v = acc[ct][reg] + b1s[ct * 16 + cl];
            unsigned int m = (unsigned int)f2bf(v);
            unsigned int p = (unsigned int)__shfl_xor((int)m, 1);
            if (!(l & 1) && row < N)
                xlb[(size_t)row * 32 + ct * 8 + (cl >> 1)] = m | (p << 16);
        }
    }
}

// ---- K2: per-bucket scan of writer counts -> segT + totals ----
__global__ __launch_bounds__(TPB) void k_colscan(
    const int* __restrict__ cntT, int* __restrict__ segT, int* __restrict__ totals, int NB)
{
    __shared__ int wsum[4];
    const int r = blockIdx.x;
    const int t = threadIdx.x;
    const int lane = t & 63, wid = t >> 6;
    int v = cntT[r * NWRITERS + t];
    int incl = v;
    for (int d = 1; d < 64; d <<= 1) {
        int n = __shfl_up(incl, d);
        if (lane >= d) incl += n;
    }
    if (lane == 63) wsum[wid] = incl;
    __syncthreads();
    int woff = 0;
    for (int w = 0; w < wid; w++) woff += wsum[w];
    int excl = woff + incl - v;
    segT[r * NWRITERS + t] = excl;
    if (t == TPB - 1) totals[r] = excl + v;
}

// ---- K3: exclusive scan of bucket totals -> bucket base (one wave) ----
__global__ void k_bucketbase(const int* __restrict__ totals, int* __restrict__ bb, int NB, int E)
{
    const int lane = threadIdx.x & 63;
    int carry = 0;
    for (int it = 0; it * 64 < NB; ++it) {
        int idx = it * 64 + lane;
        int v = (idx < NB) ? totals[idx] : 0;
        int incl = v;
        for (int d = 1; d < 64; d <<= 1) {
            int n = __shfl_up(incl, d);
            if (lane >= d) incl += n;
        }
        if (idx < NB) bb[idx] = carry + incl - v;
        carry += __shfl(incl, 63);
    }
    if (lane == 0) bb[NB] = E;
}

// ---- K4: bin edges into block-private (writer,bucket) segments ----
__global__ __launch_bounds__(TPB) void k_fillbin(
    const int* __restrict__ ei, const int* __restrict__ segT, const int* __restrict__ bb,
    unsigned int* __restrict__ recs, int E, int NB, int CH)
{
    __shared__ int lcur[1024];
    const int blk = blockIdx.x;
    const int t = threadIdx.x;
    for (int j = t; j < NB; j += TPB)
        lcur[j] = bb[j] + segT[j * NWRITERS + blk];
    __syncthreads();

    const int start = blk * CH;
    const int lim = min(E, start + CH);
    const int* src = ei;
    const int* dst = ei + E;
    int i = start + t * 4;
    for (; i + 3 < lim; i += TPB * 4) {
        vint4 d = __builtin_nontemporal_load(reinterpret_cast<const vint4*>(dst + i));
        vint4 s = __builtin_nontemporal_load(reinterpret_cast<const vint4*>(src + i));
        int p0 = atomicAdd(&lcur[d.x >> BSHIFT], 1);
        int p1 = atomicAdd(&lcur[d.y >> BSHIFT], 1);
        int p2 = atomicAdd(&lcur[d.z >> BSHIFT], 1);
        int p3 = atomicAdd(&lcur[d.w >> BSHIFT], 1);
        recs[p0] = ((unsigned int)s.x << BSHIFT) | (unsigned int)(d.x & (BNODES-1));
        recs[p1] = ((unsigned int)s.y << BSHIFT) | (unsigned int)(d.y & (BNODES-1));
        recs[p2] = ((unsigned int)s.z << BSHIFT) | (unsigned int)(d.z & (BNODES-1));
        recs[p3] = ((unsigned int)s.w << BSHIFT) | (unsigned int)(d.w & (BNODES-1));
    }
    for (i = start + ((lim - start) & ~3) + t; i < lim; i += TPB) {
        int d = dst[i];
        int p = atomicAdd(&lcur[d >> BSHIFT], 1);
        recs[p] = ((unsigned int)src[i] << BSHIFT) | (unsigned int)(d & (BNODES-1));
    }
}

// ---- K5: fused per-bucket counting-sort (in LDS) + aggregate + ReLU + GEMM2 ----
// Block r: sort its ~2048 records into LDS grouped by node, then the proven
// round-9 agg structure (8 slots x 8 lanes x uint4, 2-deep) with LDS edge reads.
__global__ __launch_bounds__(TPB) void k_aggs(
    const unsigned int* __restrict__ recs, const int* __restrict__ bb,
    const unsigned int* __restrict__ xlb,   // [N,32] u32 (bf16 pairs)
    const float* __restrict__ W2, const float* __restrict__ b2,
    float* __restrict__ out, int N)
{
    __shared__ int   sorted[CAP];        // 16 KB: src ids grouped by dst_local
    __shared__ float w2s[64 * 32];       // 8 KB
    __shared__ float b2s[32];
    __shared__ int   off[BNODES + 1];
    __shared__ int   cur[BNODES];
    __shared__ int   ws2[2];
    __shared__ float arow[4][68];

    const int r = blockIdx.x, t = threadIdx.x;
    const int lane = t & 63, wid = t >> 6;
    const int bb0 = bb[r], bb1 = bb[r + 1];
    const int cr = bb1 - bb0;

    const float4* w4 = reinterpret_cast<const float4*>(W2);
    for (int i = t; i < 512; i += TPB) {
        float4 u = w4[i];
        int o = i * 4;
        w2s[o+0] = u.x; w2s[o+1] = u.y; w2s[o+2] = u.z; w2s[o+3] = u.w;
    }
    if (t < 32) b2s[t] = b2[t];
    if (t < BNODES) cur[t] = 0;
    __syncthreads();

    // hist over this bucket's records (L2-hot re-read of recs)
    for (int i = bb0 + t; i < bb1; i += TPB)
        atomicAdd(&cur[recs[i] & (BNODES - 1)], 1);
    __syncthreads();

    // exclusive scan of 128 counters (2 waves)
    int v = 0, incl = 0;
    if (t < BNODES) {
        v = cur[t];
        incl = v;
        for (int d = 1; d < 64; d <<= 1) {
            int n = __shfl_up(incl, d);
            if (lane >= d) incl += n;
        }
        if (lane == 63) ws2[wid] = incl;
    }
    __syncthreads();
    if (t < BNODES) {
        int excl = incl - v + (wid ? ws2[0] : 0);
        off[t] = excl;
        cur[t] = excl;
        if (t == BNODES - 1) off[BNODES] = cr;
    }
    __syncthreads();

    const bool fits = (cr <= CAP);
    if (fits) {
        for (int i = bb0 + t; i < bb1; i += TPB) {
            unsigned int rec = recs[i];
            int p = atomicAdd(&cur[rec & (BNODES - 1)], 1);
            sorted[p] = (int)(rec >> BSHIFT);
        }
    }
    __syncthreads();

    const int slot = lane >> 3, b = lane & 7;     // 8 edge slots x 8 feature-lanes
    const int c = lane & 31, h = lane >> 5;       // gemm2 mapping
    const uint4* xb4 = reinterpret_cast<const uint4*>(xlb);

    for (int dl = wid; dl < BNODES; dl += 4) {
        const int node = r * BNODES + dl;
        if (node >= N) break;
        float a0=0.f,a1=0.f,a2=0.f,a3=0.f,a4=0.f,a5=0.f,a6=0.f,a7=0.f;
        if (fits) {
            const int beg = off[dl], end = off[dl + 1];
            int e = beg + slot;
            for (; e + 8 < end; e += 16) {
                int s0 = sorted[e];
                int s1 = sorted[e + 8];
                uint4 v0 = xb4[(size_t)s0 * 8 + b];
                uint4 v1 = xb4[(size_t)s1 * 8 + b];
                a0 += bflo(v0.x); a1 += bfhi(v0.x);
                a2 += bflo(v0.y); a3 += bfhi(v0.y);
                a4 += bflo(v0.z); a5 += bfhi(v0.z);
                a6 += bflo(v0.w); a7 += bfhi(v0.w);
                a0 += bflo(v1.x); a1 += bfhi(v1.x);
                a2 += bflo(v1.y); a3 += bfhi(v1.y);
                a4 += bflo(v1.z); a5 += bfhi(v1.z);
                a6 += bflo(v1.w); a7 += bfhi(v1.w);
            }
            if (e < end) {
                int s = sorted[e];
                uint4 vv = xb4[(size_t)s * 8 + b];
                a0 += bflo(vv.x); a1 += bfhi(vv.x);
                a2 += bflo(vv.y); a3 += bfhi(vv.y);
                a4 += bflo(vv.z); a5 += bfhi(vv.z);
                a6 += bflo(vv.w); a7 += bfhi(vv.w);
            }
        } else {
            // overflow fallback (prob ~0): direct filtered scan of global records
            for (int i = bb0 + slot; i < bb1; i += 8) {
                unsigned int rec = recs[i];
                if ((int)(rec & (BNODES - 1)) == dl) {
                    uint4 vv = xb4[(size_t)(rec >> BSHIFT) * 8 + b];
                    a0 += bflo(vv.x); a1 += bfhi(vv.x);
                    a2 += bflo(vv.y); a3 += bfhi(vv.y);
                    a4 += bflo(vv.z); a5 += bfhi(vv.z);
                    a6 += bflo(vv.w); a7 += bfhi(vv.w);
                }
            }
        }
        #pragma unroll
        for (int d = 8; d <= 32; d <<= 1) {
            a0 += __shfl_xor(a0, d); a1 += __shfl_xor(a1, d);
            a2 += __shfl_xor(a2, d); a3 += __shfl_xor(a3, d);
            a4 += __shfl_xor(a4, d); a5 += __shfl_xor(a5, d);
            a6 += __shfl_xor(a6, d); a7 += __shfl_xor(a7, d);
        }
        if (slot == 0) {
            uint4 sv = xb4[(size_t)node * 8 + b];   // self-loop
            float* p = &arow[wid][b * 8];
            p[0] = fmaxf(a0 + bflo(sv.x), 0.f);
            p[1] = fmaxf(a1 + bfhi(sv.x), 0.f);
            p[2] = fmaxf(a2 + bflo(sv.y), 0.f);
            p[3] = fmaxf(a3 + bfhi(sv.y), 0.f);
            p[4] = fmaxf(a4 + bflo(sv.z), 0.f);
            p[5] = fmaxf(a5 + bfhi(sv.z), 0.f);
            p[6] = fmaxf(a6 + bflo(sv.w), 0.f);
            p[7] = fmaxf(a7 + bfhi(sv.w), 0.f);
        }
        float o = 0.f;
        const float* ar = &arow[wid][h * 32];
        const float* wp = &w2s[h * 32 * 32 + c];
        #pragma unroll
        for (int kk = 0; kk < 32; kk++)
            o = fmaf(ar[kk], wp[kk * 32], o);
        o += __shfl_xor(o, 32);
        if (h == 0) out[(size_t)node * 32 + c] = o + b2s[c];
    }
}

extern "C" void kernel_launch(void* const* d_in, const int* in_sizes, int n_in,
                              void* d_out, int out_size, void* d_ws, size_t ws_size,
                              hipStream_t stream) {
    const float* x  = (const float*)d_in[0];
    const int*   ei = (const int*)d_in[1];
    const float* W1 = (const float*)d_in[2];
    const float* b1 = (const float*)d_in[3];
    const float* W2 = (const float*)d_in[4];
    const float* b2 = (const float*)d_in[5];
    float* out = (float*)d_out;

    const int N = in_sizes[0] / 128;
    const int E = in_sizes[1] / 2;
    const int NB = (N + BNODES - 1) >> BSHIFT;
    const int CH = (((E + NWRITERS - 1) / NWRITERS) + 3) & ~3;

    char* w = (char*)d_ws;
    unsigned int* xlb = (unsigned int*)w;   w += (size_t)N * 32 * 4;          // 12.8 MB
    int* cntT   = (int*)w;                  w += (size_t)NB * NWRITERS * 4;   // 800 KB
    int* segT   = (int*)w;                  w += (size_t)NB * NWRITERS * 4;   // 800 KB
    int* totals = (int*)w;                  w += ((size_t)NB * 4 + 15) & ~15ull;
    int* bbase  = (int*)w;                  w += ((size_t)(NB + 1) * 4 + 15) & ~15ull;
    unsigned int* recs = (unsigned int*)w;  // 6.4 MB

    const int nbG = (N + 63) / 64;

    hipLaunchKernelGGL(k_gemm1_hist, dim3(NWRITERS + nbG), dim3(TPB), 0, stream,
                       x, W1, b1, xlb, ei, cntT, N, E, NB, CH);
    hipLaunchKernelGGL(k_colscan, dim3(NB), dim3(TPB), 0, stream, cntT, segT, totals, NB);
    hipLaunchKernelGGL(k_bucketbase, dim3(1), dim3(64), 0, stream, totals, bbase, NB, E);
    hipLaunchKernelGGL(k_fillbin, dim3(NWRITERS), dim3(TPB), 0, stream,
                       ei, segT, bbase, recs, E, NB, CH);
    hipLaunchKernelGGL(k_aggs, dim3(NB), dim3(TPB), 0, stream,
                       recs, bbase, xlb, W2, b2, out, N);
}

// Round 12
// 131.428 us; speedup vs baseline: 6.1355x; 1.0857x over previous
//
#include <hip/hip_runtime.h>
#include <hip/hip_bf16.h>

#define TPB 256
#define BSHIFT 7                 // 128 nodes per bucket
#define BNODES (1 << BSHIFT)
#define NWRITERS 256             // edge-chunk writer blocks

typedef int vint4 __attribute__((ext_vector_type(4)));
typedef __attribute__((ext_vector_type(8))) short short8v;   // 8 bf16 (4 VGPRs)
typedef __attribute__((ext_vector_type(4))) float f32x4;

// f32 -> bf16 bits, RNE
__device__ __forceinline__ unsigned short f2bf(float f) {
    unsigned int u = __float_as_uint(f);
    u += 0x7fffu + ((u >> 16) & 1u);
    return (unsigned short)(u >> 16);
}
__device__ __forceinline__ float bflo(unsigned int u) { return __uint_as_float(u << 16); }
__device__ __forceinline__ float bfhi(unsigned int u) { return __uint_as_float(u & 0xffff0000u); }

// ---- K1: fused [hist: per-writer bucket counts] + [gemm1 MFMA: xlb = bf16(x@W1+b1)] ----
__global__ __launch_bounds__(TPB) void k_gemm1_hist(
    const float* __restrict__ x, const float* __restrict__ W1, const float* __restrict__ b1,
    unsigned int* __restrict__ xlb,
    const int* __restrict__ ei, int* __restrict__ cntT,
    int N, int E, int NB, int CH)
{
    __shared__ unsigned short wT[64 * 136];   // W1^T bf16, stride 136 (2-way = free)
    __shared__ float b1s[64];
    __shared__ int   lcnt[1024];

    const int t = threadIdx.x;

    if ((int)blockIdx.x < NWRITERS) {
        const int hb = blockIdx.x;
        const int start = hb * CH;
        const int lim = min(E, start + CH);
        for (int j = t; j < NB; j += TPB) lcnt[j] = 0;
        __syncthreads();
        const int* dst = ei + E;
        int i = start + t * 4;
        for (; i + 3 < lim; i += TPB * 4) {
            vint4 d = __builtin_nontemporal_load(reinterpret_cast<const vint4*>(dst + i));
            atomicAdd(&lcnt[d.x >> BSHIFT], 1);
            atomicAdd(&lcnt[d.y >> BSHIFT], 1);
            atomicAdd(&lcnt[d.z >> BSHIFT], 1);
            atomicAdd(&lcnt[d.w >> BSHIFT], 1);
        }
        for (i = start + ((lim - start) & ~3) + t; i < lim; i += TPB)
            atomicAdd(&lcnt[dst[i] >> BSHIFT], 1);
        __syncthreads();
        for (int j = t; j < NB; j += TPB) cntT[j * NWRITERS + hb] = lcnt[j];
        return;
    }

    // ---- gemm1 MFMA: 4 waves x 16 rows = 64 rows/block ----
    for (int i = t; i < 2048; i += TPB) {
        int k = i >> 4, cw = (i & 15) * 4;
        float4 u = reinterpret_cast<const float4*>(W1)[i];
        wT[(cw + 0) * 136 + k] = f2bf(u.x);
        wT[(cw + 1) * 136 + k] = f2bf(u.y);
        wT[(cw + 2) * 136 + k] = f2bf(u.z);
        wT[(cw + 3) * 136 + k] = f2bf(u.w);
    }
    if (t < 64) b1s[t] = b1[t];
    __syncthreads();

    const int l = t & 63, wid = t >> 6;
    const int cl = l & 15, kg = l >> 4;
    const int rw = ((int)blockIdx.x - NWRITERS) * 64 + wid * 16;
    if (rw >= N) return;
    const int r = rw + cl;

    const float4* xp4 = reinterpret_cast<const float4*>(x) + ((size_t)min(r, N - 1) * 32 + kg * 2);

    f32x4 acc[4] = {};
    #pragma unroll
    for (int kt = 0; kt < 4; ++kt) {
        float4 fA = xp4[kt * 8];
        float4 fB = xp4[kt * 8 + 1];
        short8v a;
        a[0] = (short)f2bf(fA.x); a[1] = (short)f2bf(fA.y);
        a[2] = (short)f2bf(fA.z); a[3] = (short)f2bf(fA.w);
        a[4] = (short)f2bf(fB.x); a[5] = (short)f2bf(fB.y);
        a[6] = (short)f2bf(fB.z); a[7] = (short)f2bf(fB.w);
        #pragma unroll
        for (int ct = 0; ct < 4; ++ct) {
            short8v b = *reinterpret_cast<const short8v*>(
                &wT[(ct * 16 + cl) * 136 + kt * 32 + kg * 8]);
            acc[ct] = __builtin_amdgcn_mfma_f32_16x16x32_bf16(a, b, acc[ct], 0, 0, 0);
        }
    }

    #pragma unroll
    for (int ct = 0; ct < 4; ++ct) {
        #pragma unroll
        for (int reg = 0; reg < 4; ++reg) {
            int row = rw + kg * 4 + reg;
            float v = acc[ct][reg] + b1s[ct * 16 + cl];
            unsigned int m = (unsigned int)f2bf(v);
            unsigned int p = (unsigned int)__shfl_xor((int)m, 1);
            if (!(l & 1) && row < N)
                xlb[(size_t)row * 32 + ct * 8 + (cl >> 1)] = m | (p << 16);
        }
    }
}

// ---- K2: per-bucket scan of writer counts -> segT + totals ----
__global__ __launch_bounds__(TPB) void k_colscan(
    const int* __restrict__ cntT, int* __restrict__ segT, int* __restrict__ totals, int NB)
{
    __shared__ int wsum[4];
    const int r = blockIdx.x;
    const int t = threadIdx.x;
    const int lane = t & 63, wid = t >> 6;
    int v = cntT[r * NWRITERS + t];
    int incl = v;
    for (int d = 1; d < 64; d <<= 1) {
        int n = __shfl_up(incl, d);
        if (lane >= d) incl += n;
    }
    if (lane == 63) wsum[wid] = incl;
    __syncthreads();
    int woff = 0;
    for (int w = 0; w < wid; w++) woff += wsum[w];
    int excl = woff + incl - v;
    segT[r * NWRITERS + t] = excl;
    if (t == TPB - 1) totals[r] = excl + v;
}

// ---- K3: exclusive scan of bucket totals -> bucket base (one wave) ----
__global__ void k_bucketbase(const int* __restrict__ totals, int* __restrict__ bb, int NB, int E)
{
    const int lane = threadIdx.x & 63;
    int carry = 0;
    for (int it = 0; it * 64 < NB; ++it) {
        int idx = it * 64 + lane;
        int v = (idx < NB) ? totals[idx] : 0;
        int incl = v;
        for (int d = 1; d < 64; d <<= 1) {
            int n = __shfl_up(incl, d);
            if (lane >= d) incl += n;
        }
        if (idx < NB) bb[idx] = carry + incl - v;
        carry += __shfl(incl, 63);
    }
    if (lane == 0) bb[NB] = E;
}

// ---- K4: bin edges into block-private (writer,bucket) segments ----
__global__ __launch_bounds__(TPB) void k_fillbin(
    const int* __restrict__ ei, const int* __restrict__ segT, const int* __restrict__ bb,
    unsigned int* __restrict__ recs, int E, int NB, int CH)
{
    __shared__ int lcur[1024];
    const int blk = blockIdx.x;
    const int t = threadIdx.x;
    for (int j = t; j < NB; j += TPB)
        lcur[j] = bb[j] + segT[j * NWRITERS + blk];
    __syncthreads();

    const int start = blk * CH;
    const int lim = min(E, start + CH);
    const int* src = ei;
    const int* dst = ei + E;
    int i = start + t * 4;
    for (; i + 3 < lim; i += TPB * 4) {
        vint4 d = __builtin_nontemporal_load(reinterpret_cast<const vint4*>(dst + i));
        vint4 s = __builtin_nontemporal_load(reinterpret_cast<const vint4*>(src + i));
        int p0 = atomicAdd(&lcur[d.x >> BSHIFT], 1);
        int p1 = atomicAdd(&lcur[d.y >> BSHIFT], 1);
        int p2 = atomicAdd(&lcur[d.z >> BSHIFT], 1);
        int p3 = atomicAdd(&lcur[d.w >> BSHIFT], 1);
        recs[p0] = ((unsigned int)s.x << BSHIFT) | (unsigned int)(d.x & (BNODES-1));
        recs[p1] = ((unsigned int)s.y << BSHIFT) | (unsigned int)(d.y & (BNODES-1));
        recs[p2] = ((unsigned int)s.z << BSHIFT) | (unsigned int)(d.z & (BNODES-1));
        recs[p3] = ((unsigned int)s.w << BSHIFT) | (unsigned int)(d.w & (BNODES-1));
    }
    for (i = start + ((lim - start) & ~3) + t; i < lim; i += TPB) {
        int d = dst[i];
        int p = atomicAdd(&lcur[d >> BSHIFT], 1);
        recs[p] = ((unsigned int)src[i] << BSHIFT) | (unsigned int)(d & (BNODES-1));
    }
}

// ---- K5: per-bucket counting sort -> node-sorted esrc + global off ----
__global__ __launch_bounds__(TPB) void k_bsort(
    const unsigned int* __restrict__ recs, const int* __restrict__ bb,
    int* __restrict__ esrc, int* __restrict__ off, int N, int NB, int E)
{
    __shared__ int h[BNODES];
    __shared__ int cur[BNODES];
    __shared__ int ws2[2];

    const int r = blockIdx.x;
    const int t = threadIdx.x;
    const int bb0 = bb[r], bb1 = bb[r + 1];

    if (t < BNODES) h[t] = 0;
    __syncthreads();
    for (int i = bb0 + t; i < bb1; i += TPB)
        atomicAdd(&h[recs[i] & (BNODES - 1)], 1);
    __syncthreads();

    int v = 0, incl = 0;
    const int lane = t & 63, w = t >> 6;
    if (t < BNODES) {
        v = h[t];
        incl = v;
        for (int d = 1; d < 64; d <<= 1) {
            int n = __shfl_up(incl, d);
            if (lane >= d) incl += n;
        }
        if (lane == 63) ws2[w] = incl;
    }
    __syncthreads();
    if (t < BNODES) {
        int excl = incl - v + (w ? ws2[0] : 0);
        cur[t] = bb0 + excl;
        int node = r * BNODES + t;
        if (node < N) off[node] = bb0 + excl;
    }
    if (r == NB - 1 && t == 0) off[N] = E;
    __syncthreads();

    for (int i = bb0 + t; i < bb1; i += TPB) {
        unsigned int rec = recs[i];
        int p = atomicAdd(&cur[rec & (BNODES - 1)], 1);
        esrc[p] = (int)(rec >> BSHIFT);
    }
}

// ---- K6: aggregate + ReLU + GEMM2 (round-9 structure, 4x the blocks for TLP) ----
#define AGG_BLOCKS 8192
__global__ __launch_bounds__(TPB) void k_agg(
    const unsigned int* __restrict__ xlb,  // [N,32] u32 (bf16 pairs)
    const int* __restrict__ off,           // [N+1]
    const int* __restrict__ esrc,          // [E]
    const float* __restrict__ W2,          // [64,32]
    const float* __restrict__ b2,          // [32]
    float* __restrict__ out, int N)
{
    __shared__ float w2s[64 * 32];
    __shared__ float b2s[32];
    __shared__ float arow[4][68];

    const int t = threadIdx.x;
    const float4* w4 = reinterpret_cast<const float4*>(W2);
    for (int i = t; i < 512; i += TPB) {
        float4 u = w4[i];
        int o = i * 4;
        w2s[o+0] = u.x; w2s[o+1] = u.y; w2s[o+2] = u.z; w2s[o+3] = u.w;
    }
    if (t < 32) b2s[t] = b2[t];
    __syncthreads();

    const int wid = t >> 6, lane = t & 63;
    const int slot = lane >> 3, b = lane & 7;
    const int c = lane & 31, h = lane >> 5;
    const uint4* xb4 = reinterpret_cast<const uint4*>(xlb);

    for (int node = blockIdx.x * 4 + wid; node < N; node += gridDim.x * 4) {
        const int beg = off[node], end = off[node + 1];
        float a0=0.f,a1=0.f,a2=0.f,a3=0.f,a4=0.f,a5=0.f,a6=0.f,a7=0.f;
        int e = beg + slot;
        for (; e + 8 < end; e += 16) {
            int s0 = esrc[e];
            int s1 = esrc[e + 8];
            uint4 v0 = xb4[(size_t)s0 * 8 + b];
            uint4 v1 = xb4[(size_t)s1 * 8 + b];
            a0 += bflo(v0.x); a1 += bfhi(v0.x);
            a2 += bflo(v0.y); a3 += bfhi(v0.y);
            a4 += bflo(v0.z); a5 += bfhi(v0.z);
            a6 += bflo(v0.w); a7 += bfhi(v0.w);
            a0 += bflo(v1.x); a1 += bfhi(v1.x);
            a2 += bflo(v1.y); a3 += bfhi(v1.y);
            a4 += bflo(v1.z); a5 += bfhi(v1.z);
            a6 += bflo(v1.w); a7 += bfhi(v1.w);
        }
        if (e < end) {
            int s = esrc[e];
            uint4 v = xb4[(size_t)s * 8 + b];
            a0 += bflo(v.x); a1 += bfhi(v.x);
            a2 += bflo(v.y); a3 += bfhi(v.y);
            a4 += bflo(v.z); a5 += bfhi(v.z);
            a6 += bflo(v.w); a7 += bfhi(v.w);
        }
        #pragma unroll
        for (int d = 8; d <= 32; d <<= 1) {
            a0 += __shfl_xor(a0, d); a1 += __shfl_xor(a1, d);
            a2 += __shfl_xor(a2, d); a3 += __shfl_xor(a3, d);
            a4 += __shfl_xor(a4, d); a5 += __shfl_xor(a5, d);
            a6 += __shfl_xor(a6, d); a7 += __shfl_xor(a7, d);
        }
        if (slot == 0) {
            uint4 sv = xb4[(size_t)node * 8 + b];
            float* p = &arow[wid][b * 8];
            p[0] = fmaxf(a0 + bflo(sv.x), 0.f);
            p[1] = fmaxf(a1 + bfhi(sv.x), 0.f);
            p[2] = fmaxf(a2 + bflo(sv.y), 0.f);
            p[3] = fmaxf(a3 + bfhi(sv.y), 0.f);
            p[4] = fmaxf(a4 + bflo(sv.z), 0.f);
            p[5] = fmaxf(a5 + bfhi(sv.z), 0.f);
            p[6] = fmaxf(a6 + bflo(sv.w), 0.f);
            p[7] = fmaxf(a7 + bfhi(sv.w), 0.f);
        }
        float o = 0.f;
        const float* ar = &arow[wid][h * 32];
        const float* wp = &w2s[h * 32 * 32 + c];
        #pragma unroll
        for (int kk = 0; kk < 32; kk++)
            o = fmaf(ar[kk], wp[kk * 32], o);
        o += __shfl_xor(o, 32);
        if (h == 0) out[(size_t)node * 32 + c] = o + b2s[c];
    }
}

extern "C" void kernel_launch(void* const* d_in, const int* in_sizes, int n_in,
                              void* d_out, int out_size, void* d_ws, size_t ws_size,
                              hipStream_t stream) {
    const float* x  = (const float*)d_in[0];
    const int*   ei = (const int*)d_in[1];
    const float* W1 = (const float*)d_in[2];
    const float* b1 = (const float*)d_in[3];
    const float* W2 = (const float*)d_in[4];
    const float* b2 = (const float*)d_in[5];
    float* out = (float*)d_out;

    const int N = in_sizes[0] / 128;
    const int E = in_sizes[1] / 2;
    const int NB = (N + BNODES - 1) >> BSHIFT;
    const int CH = (((E + NWRITERS - 1) / NWRITERS) + 3) & ~3;

    char* w = (char*)d_ws;
    unsigned int* xlb = (unsigned int*)w;   w += (size_t)N * 32 * 4;          // 12.8 MB
    int* cntT   = (int*)w;                  w += (size_t)NB * NWRITERS * 4;   // 800 KB
    int* segT   = (int*)w;                  w += (size_t)NB * NWRITERS * 4;   // 800 KB
    int* totals = (int*)w;                  w += ((size_t)NB * 4 + 15) & ~15ull;
    int* bbase  = (int*)w;                  w += ((size_t)(NB + 1) * 4 + 15) & ~15ull;
    int* off    = (int*)w;                  w += ((size_t)(N + 1) * 4 + 15) & ~15ull;
    unsigned int* recs = (unsigned int*)w;  w += (size_t)E * 4;               // 6.4 MB
    int* esrc   = (int*)w;                  // 6.4 MB

    const int nbG = (N + 63) / 64;

    hipLaunchKernelGGL(k_gemm1_hist, dim3(NWRITERS + nbG), dim3(TPB), 0, stream,
                       x, W1, b1, xlb, ei, cntT, N, E, NB, CH);
    hipLaunchKernelGGL(k_colscan, dim3(NB), dim3(TPB), 0, stream, cntT, segT, totals, NB);
    hipLaunchKernelGGL(k_bucketbase, dim3(1), dim3(64), 0, stream, totals, bbase, NB, E);
    hipLaunchKernelGGL(k_fillbin, dim3(NWRITERS), dim3(TPB), 0, stream,
                       ei, segT, bbase, recs, E, NB, CH);
    hipLaunchKernelGGL(k_bsort, dim3(NB), dim3(TPB), 0, stream,
                       recs, bbase, esrc, off, N, NB, E);
    hipLaunchKernelGGL(k_agg, dim3(AGG_BLOCKS), dim3(TPB), 0, stream,
                       xlb, off, esrc, W2, b2, out, N);
}